// Round 1
// baseline (194.438 us; speedup 1.0000x reference)
//
#include <hip/hip_runtime.h>
#include <hip/hip_bf16.h>
#include <stdint.h>

#define B_ 4
#define P_ 256
#define S_ 4096
#define D_ 1024
#define H_ 16
#define HD_ 64

typedef __attribute__((ext_vector_type(8))) short short8;
typedef __attribute__((ext_vector_type(4))) short short4v;
typedef __attribute__((ext_vector_type(4))) float f32x4;

__device__ __forceinline__ float b2f(short s) {
  return __uint_as_float(((unsigned)(unsigned short)s) << 16);
}
__device__ __forceinline__ short f2bf(float f) {
  unsigned u = __float_as_uint(f);
  unsigned r = (u + 0x7fffu + ((u >> 16) & 1u)) >> 16;
  return (short)(unsigned short)r;
}

// ---------------------------------------------------------------------------
// prep: convert byte_hidden + 4 weights to bf16; LayerNorm(patch_emb) -> bf16
// grid: 8192 (X) + 2048 (weights) + 1024 (LN rows) = 11264 blocks x 256
// ---------------------------------------------------------------------------
__global__ __launch_bounds__(256) void prep_kernel(
    const float* __restrict__ xbytes, const float* __restrict__ pe,
    const float* __restrict__ gamma, const float* __restrict__ beta,
    const float* __restrict__ wq, const float* __restrict__ wk,
    const float* __restrict__ wv, const float* __restrict__ wo,
    short* __restrict__ Xb, short* __restrict__ wqb, short* __restrict__ wkb,
    short* __restrict__ wvb, short* __restrict__ wob, short* __restrict__ qx)
{
  const int bid = blockIdx.x;
  const int tid = threadIdx.x;
  if (bid < 8192) {
    const size_t base = (size_t)bid * 2048 + (size_t)tid * 8;
    const float4 f0 = *(const float4*)(xbytes + base);
    const float4 f1 = *(const float4*)(xbytes + base + 4);
    short8 o;
    o[0] = f2bf(f0.x); o[1] = f2bf(f0.y); o[2] = f2bf(f0.z); o[3] = f2bf(f0.w);
    o[4] = f2bf(f1.x); o[5] = f2bf(f1.y); o[6] = f2bf(f1.z); o[7] = f2bf(f1.w);
    *(short8*)(Xb + base) = o;
  } else if (bid < 8192 + 2048) {
    const int r = bid - 8192;
    const int wi = r >> 9;
    const size_t base = (size_t)(r & 511) * 2048 + (size_t)tid * 8;
    const float* src; short* dst;
    if (wi == 0)      { src = wq; dst = wqb; }
    else if (wi == 1) { src = wk; dst = wkb; }
    else if (wi == 2) { src = wv; dst = wvb; }
    else              { src = wo; dst = wob; }
    const float4 f0 = *(const float4*)(src + base);
    const float4 f1 = *(const float4*)(src + base + 4);
    short8 o;
    o[0] = f2bf(f0.x); o[1] = f2bf(f0.y); o[2] = f2bf(f0.z); o[3] = f2bf(f0.w);
    o[4] = f2bf(f1.x); o[5] = f2bf(f1.y); o[6] = f2bf(f1.z); o[7] = f2bf(f1.w);
    *(short8*)(dst + base) = o;
  } else {
    // LayerNorm: one block per row of patch_embeddings (B*P = 1024 rows)
    const int row = bid - 10240;
    const int c = tid * 4;
    const float4 x = *(const float4*)(pe + (size_t)row * D_ + c);
    float s1 = x.x + x.y + x.z + x.w;
    float s2 = x.x * x.x + x.y * x.y + x.z * x.z + x.w * x.w;
    #pragma unroll
    for (int off = 32; off >= 1; off >>= 1) {
      s1 += __shfl_xor(s1, off, 64);
      s2 += __shfl_xor(s2, off, 64);
    }
    __shared__ float red[8];
    const int wid = tid >> 6, lane = tid & 63;
    if (lane == 0) { red[wid] = s1; red[4 + wid] = s2; }
    __syncthreads();
    s1 = red[0] + red[1] + red[2] + red[3];
    s2 = red[4] + red[5] + red[6] + red[7];
    const float mu = s1 * (1.0f / D_);
    const float var = s2 * (1.0f / D_) - mu * mu;
    const float rs = rsqrtf(var + 1e-5f);
    const float4 g = *(const float4*)(gamma + c);
    const float4 bt = *(const float4*)(beta + c);
    short4v o;
    o[0] = f2bf((x.x - mu) * rs * g.x + bt.x);
    o[1] = f2bf((x.y - mu) * rs * g.y + bt.y);
    o[2] = f2bf((x.z - mu) * rs * g.z + bt.z);
    o[3] = f2bf((x.w - mu) * rs * g.w + bt.w);
    *(short4v*)(qx + (size_t)row * D_ + c) = o;
  }
}

// ---------------------------------------------------------------------------
// GEMM core: C[M,N] = A[M,K] * W[N,K]^T, bf16 in, f32 acc, 128x128 tile,
// BK=64, 4 waves (2x2), each wave 64x64 = 4x4 frags of mfma_f32_16x16x32_bf16.
// global_load_lds width=16, 2-barrier K-loop (m97 structure).
// ---------------------------------------------------------------------------
#define BM 128
#define BN 128
#define BK 64

__device__ __forceinline__ void gemm_core(
    const short* __restrict__ A, const short* __restrict__ W,
    int mt, int nt, int Kd, f32x4 acc[4][4], short* As, short* Bs)
{
  const int tid = threadIdx.x;
  const int wid = tid >> 6, lane = tid & 63;
  const int lr = lane & 15, lk = lane >> 4;
  const int seg_row = lane >> 3;            // 0..7 rows within a 1KB segment
  const int seg_col = (lane & 7) * 8;       // element col within 64-wide row
  const int wr = wid >> 1, wc = wid & 1;

  for (int kt = 0; kt < Kd; kt += BK) {
    __syncthreads();
    #pragma unroll
    for (int j = 0; j < 4; ++j) {
      const int s = wid * 4 + j;            // segment 0..15 (8 rows each)
      const size_t arow = (size_t)(mt * BM + s * 8 + seg_row);
      const size_t brow = (size_t)(nt * BN + s * 8 + seg_row);
      __builtin_amdgcn_global_load_lds(
          (const __attribute__((address_space(1))) void*)(A + arow * Kd + kt + seg_col),
          (__attribute__((address_space(3))) void*)(As + s * 512), 16, 0, 0);
      __builtin_amdgcn_global_load_lds(
          (const __attribute__((address_space(1))) void*)(W + brow * Kd + kt + seg_col),
          (__attribute__((address_space(3))) void*)(Bs + s * 512), 16, 0, 0);
    }
    asm volatile("s_waitcnt vmcnt(0)" ::: "memory");
    __syncthreads();
    #pragma unroll
    for (int ks = 0; ks < 2; ++ks) {
      short8 a[4], bfr[4];
      #pragma unroll
      for (int m = 0; m < 4; ++m)
        a[m] = *(const short8*)(As + (wr * 64 + m * 16 + lr) * BK + ks * 32 + lk * 8);
      #pragma unroll
      for (int n = 0; n < 4; ++n)
        bfr[n] = *(const short8*)(Bs + (wc * 64 + n * 16 + lr) * BK + ks * 32 + lk * 8);
      #pragma unroll
      for (int m = 0; m < 4; ++m)
        #pragma unroll
        for (int n = 0; n < 4; ++n)
          acc[m][n] = __builtin_amdgcn_mfma_f32_16x16x32_bf16(a[m], bfr[n], acc[m][n], 0, 0, 0);
    }
  }
}

// K,V,Q projections in one launch. bids: [0,1024) K, [1024,2048) V, [2048,2112) Q
__global__ __launch_bounds__(256) void gemm_kvq(
    const short* __restrict__ Xb, const short* __restrict__ qx,
    const short* __restrict__ wqb, const short* __restrict__ wkb,
    const short* __restrict__ wvb,
    const float* __restrict__ b_q, const float* __restrict__ b_k,
    const float* __restrict__ b_v,
    short* __restrict__ Ko, short* __restrict__ Vo, short* __restrict__ Qo)
{
  __shared__ __align__(16) short As[BM * BK];
  __shared__ __align__(16) short Bs[BN * BK];
  int bid = blockIdx.x;
  const short* A; const short* W; const float* bias; short* C;
  if (bid < 1024)      { A = Xb; W = wkb; bias = b_k; C = Ko; }
  else if (bid < 2048) { bid -= 1024; A = Xb; W = wvb; bias = b_v; C = Vo; }
  else                 { bid -= 2048; A = qx; W = wqb; bias = b_q; C = Qo; }
  const int mt = bid >> 3, nt = bid & 7;

  f32x4 acc[4][4] = {};
  gemm_core(A, W, mt, nt, D_, acc, As, Bs);

  const int lane = threadIdx.x & 63;
  const int wid = threadIdx.x >> 6;
  const int wr = wid >> 1, wc = wid & 1;
  const int lr = lane & 15, lq = lane >> 4;
  #pragma unroll
  for (int n = 0; n < 4; ++n) {
    const int col = nt * BN + wc * 64 + n * 16 + lr;
    const float bv = bias[col];
    #pragma unroll
    for (int m = 0; m < 4; ++m) {
      const int row0 = mt * BM + wr * 64 + m * 16 + lq * 4;
      #pragma unroll
      for (int i = 0; i < 4; ++i)
        C[(size_t)(row0 + i) * D_ + col] = f2bf(acc[m][n][i] + bv);
    }
  }
}

// O projection + bias + residual, fp32 out. 64 blocks.
__global__ __launch_bounds__(256) void gemm_o(
    const short* __restrict__ AO, const short* __restrict__ wob,
    const float* __restrict__ b_o, const float* __restrict__ pe,
    float* __restrict__ out)
{
  __shared__ __align__(16) short As[BM * BK];
  __shared__ __align__(16) short Bs[BN * BK];
  const int bid = blockIdx.x;
  const int mt = bid >> 3, nt = bid & 7;

  f32x4 acc[4][4] = {};
  gemm_core(AO, wob, mt, nt, D_, acc, As, Bs);

  const int lane = threadIdx.x & 63;
  const int wid = threadIdx.x >> 6;
  const int wr = wid >> 1, wc = wid & 1;
  const int lr = lane & 15, lq = lane >> 4;
  #pragma unroll
  for (int n = 0; n < 4; ++n) {
    const int col = nt * BN + wc * 64 + n * 16 + lr;
    const float bv = b_o[col];
    #pragma unroll
    for (int m = 0; m < 4; ++m) {
      const int row0 = mt * BM + wr * 64 + m * 16 + lq * 4;
      #pragma unroll
      for (int i = 0; i < 4; ++i) {
        const size_t idx = (size_t)(row0 + i) * D_ + col;
        out[idx] = acc[m][n][i] + bv + pe[idx];
      }
    }
  }
}

// ---------------------------------------------------------------------------
// Attention: 1 block per (b,p), 4 waves x 4 heads. lane = (tq 0..15, dg 0..3).
// Online softmax over 16-wide chunks of the span; matches reference semantics
// including the all-masked/invalid-span uniform fallback.
// ---------------------------------------------------------------------------
__global__ __launch_bounds__(256) void attn_kernel(
    const short* __restrict__ Q, const short* __restrict__ K,
    const short* __restrict__ V, const int* __restrict__ pos,
    const float* __restrict__ mask, short* __restrict__ O)
{
  const int bp = blockIdx.x;
  const int b = bp >> 8;
  const int tid = threadIdx.x;
  const int wid = tid >> 6, lane = tid & 63;
  const int tq = lane & 15, dg = lane >> 4;

  // int64-vs-int32 layout probe: patch 0's end >= 1 always; int64 high word = 0
  const bool is64 = (pos[1] == 0);
  const int start = is64 ? pos[4 * bp]     : pos[2 * bp];
  const int end   = is64 ? pos[4 * bp + 2] : pos[2 * bp + 1];
  const bool valid = (start < S_) && (end <= S_) && (start < end);
  const int lo = valid ? (start < 0 ? 0 : start) : 0;
  const int hi = valid ? end : 0;

  for (int hh = 0; hh < 4; ++hh) {
    const int h = wid * 4 + hh;
    const short* qp = Q + (size_t)bp * D_ + h * HD_ + dg * 16;
    const short8 q0 = *(const short8*)qp;
    const short8 q1 = *(const short8*)(qp + 8);
    float qf[16];
    #pragma unroll
    for (int j = 0; j < 8; ++j) { qf[j] = b2f(q0[j]); qf[8 + j] = b2f(q1[j]); }

    float mrun = -3.0e38f, denom = 0.f, oacc = 0.f;
    for (int c0 = lo; c0 < hi; c0 += 16) {
      const int t = c0 + tq;
      const bool ok = (t < hi) && (mask[(size_t)b * S_ + t] != 0.f);
      float part = 0.f;
      if (ok) {
        const short* kp = K + ((size_t)b * S_ + t) * D_ + h * HD_ + dg * 16;
        const short8 k0 = *(const short8*)kp;
        const short8 k1 = *(const short8*)(kp + 8);
        #pragma unroll
        for (int j = 0; j < 8; ++j) part += qf[j] * b2f(k0[j]);
        #pragma unroll
        for (int j = 0; j < 8; ++j) part += qf[8 + j] * b2f(k1[j]);
      }
      part += __shfl_xor(part, 16, 64);
      part += __shfl_xor(part, 32, 64);
      const float sc = ok ? part * 0.125f : -3.0e38f;
      float cm = sc;
      cm = fmaxf(cm, __shfl_xor(cm, 1, 64));
      cm = fmaxf(cm, __shfl_xor(cm, 2, 64));
      cm = fmaxf(cm, __shfl_xor(cm, 4, 64));
      cm = fmaxf(cm, __shfl_xor(cm, 8, 64));
      const float nm = fmaxf(mrun, cm);
      if (nm <= -1.0e38f) continue;        // nothing allowed so far
      const float r = __expf(mrun - nm);   // mrun=-3e38 -> 0
      const float w = ok ? __expf(sc - nm) : 0.f;
      float ws = w;
      ws += __shfl_xor(ws, 1, 64);
      ws += __shfl_xor(ws, 2, 64);
      ws += __shfl_xor(ws, 4, 64);
      ws += __shfl_xor(ws, 8, 64);
      denom = denom * r + ws;
      oacc *= r;
      #pragma unroll
      for (int k2 = 0; k2 < 16; ++k2) {
        const float wk = __shfl(w, k2, 64);   // uniform across wave
        if (wk > 0.f) {
          oacc += wk * b2f(V[((size_t)b * S_ + c0 + k2) * D_ + h * HD_ + lane]);
        }
      }
      mrun = nm;
    }
    float res;
    if (denom > 0.f) {
      res = oacc / denom;
    } else {
      // reference: softmax over all -1e9 -> uniform over ALL S positions
      float sum = 0.f;
      for (int s0 = 0; s0 < S_; ++s0)
        sum += b2f(V[((size_t)b * S_ + s0) * D_ + h * HD_ + lane]);
      res = sum * (1.0f / S_);
    }
    O[(size_t)bp * D_ + h * HD_ + lane] = f2bf(res);
  }
}

// ---------------------------------------------------------------------------
extern "C" void kernel_launch(void* const* d_in, const int* in_sizes, int n_in,
                              void* d_out, int out_size, void* d_ws, size_t ws_size,
                              hipStream_t stream)
{
  const float* pe    = (const float*)d_in[0];
  const float* xby   = (const float*)d_in[1];
  const int*   pos   = (const int*)d_in[2];
  const float* mask  = (const float*)d_in[3];
  const float* gamma = (const float*)d_in[4];
  const float* beta  = (const float*)d_in[5];
  const float* w_q   = (const float*)d_in[6];
  const float* b_q   = (const float*)d_in[7];
  const float* w_k   = (const float*)d_in[8];
  const float* b_k   = (const float*)d_in[9];
  const float* w_v   = (const float*)d_in[10];
  const float* b_v   = (const float*)d_in[11];
  const float* w_o   = (const float*)d_in[12];
  const float* b_o   = (const float*)d_in[13];

  char* ws = (char*)d_ws;
  short* Xb  = (short*)(ws);                 // 32 MB: byte_hidden bf16 [16384][1024]
  short* Ko  = (short*)(ws + 33554432);      // 32 MB: K bf16
  short* Vo  = (short*)(ws + 67108864);      // 32 MB: V bf16
  short* wqb = (short*)(ws + 100663296);     // 2 MB each: bf16 weights
  short* wkb = (short*)(ws + 102760448);
  short* wvb = (short*)(ws + 104857600);
  short* wob = (short*)(ws + 106954752);
  short* qx  = (short*)(ws + 109051904);     // 2 MB: LN(patch_emb) bf16
  short* Qo  = (short*)(ws + 111149056);     // 2 MB: Q bf16
  short* AO  = (short*)(ws + 113246208);     // 2 MB: attention out bf16
  (void)in_sizes; (void)n_in; (void)out_size; (void)ws_size;

  prep_kernel<<<11264, 256, 0, stream>>>(xby, pe, gamma, beta, w_q, w_k, w_v, w_o,
                                         Xb, wqb, wkb, wvb, wob, qx);
  gemm_kvq<<<2112, 256, 0, stream>>>(Xb, qx, wqb, wkb, wvb, b_q, b_k, b_v, Ko, Vo, Qo);
  attn_kernel<<<1024, 256, 0, stream>>>(Qo, Ko, Vo, pos, mask, AO);
  gemm_o<<<64, 256, 0, stream>>>(AO, wob, b_o, pe, (float*)d_out);
}